// Round 1
// baseline (589.236 us; speedup 1.0000x reference)
//
#include <hip/hip_runtime.h>
#include <math.h>

#define BB 64
#define QQ 600
#define NT 80
#define NC 92
#define SLOTS 10   // ceil(QQ/64)

// ---------------------------------------------------------------------------
// Kernel 1: cost matrix, stored TRANSPOSED for the LSA: cost[b][t][q]
//   cost = 1*(-softmax(logits)[label_t]) + 5*L1(pbox,tbox) + 2*(-GIoU)
// op order matches the JAX reference so fp32 results agree to ~ulp.
// ---------------------------------------------------------------------------
__global__ __launch_bounds__(256) void cost_kernel(
    const float* __restrict__ logits,   // (B,Q,NC)
    const float* __restrict__ pboxes,   // (B,Q,4)
    const int*   __restrict__ tlabels,  // (B,NT)
    const float* __restrict__ tboxes,   // (B,NT,4)
    float* __restrict__ cost)           // (B,NT,QQ)
{
    __shared__ float s_tb[NT * 4];
    __shared__ int   s_tl[NT];
    const int b     = blockIdx.x / 3;   // 3 chunks of 256 threads cover Q=600
    const int chunk = blockIdx.x % 3;
    const int tid   = threadIdx.x;
    for (int i = tid; i < NT * 4; i += 256) s_tb[i] = tboxes[b * NT * 4 + i];
    for (int i = tid; i < NT;     i += 256) s_tl[i] = tlabels[b * NT + i];
    __syncthreads();
    const int q = chunk * 256 + tid;
    if (q >= QQ) return;

    const float* lrow = logits + ((size_t)b * QQ + q) * NC;
    float m = -INFINITY;
    for (int c = 0; c < NC; ++c) m = fmaxf(m, lrow[c]);
    float s = 0.f;
    for (int c = 0; c < NC; ++c) s += expf(lrow[c] - m);

    const float* pb = pboxes + ((size_t)b * QQ + q) * 4;
    const float px1 = pb[0], py1 = pb[1], px2 = pb[2], py2 = pb[3];
    const float pa = (px2 - px1) * (py2 - py1);

    float* crow = cost + (size_t)b * NT * QQ + q;
    for (int t = 0; t < NT; ++t) {
        const float cc = -(expf(lrow[s_tl[t]] - m) / s);
        const float tx1 = s_tb[t*4+0], ty1 = s_tb[t*4+1];
        const float tx2 = s_tb[t*4+2], ty2 = s_tb[t*4+3];
        const float cb = fabsf(px1-tx1) + fabsf(py1-ty1)
                       + fabsf(px2-tx2) + fabsf(py2-ty2);
        const float ta = (tx2 - tx1) * (ty2 - ty1);
        const float iw = fmaxf(fminf(px2, tx2) - fmaxf(px1, tx1), 0.f);
        const float ih = fmaxf(fminf(py2, ty2) - fmaxf(py1, ty1), 0.f);
        const float inter = iw * ih;
        const float uni   = pa + ta - inter;
        const float iou   = inter / uni;
        const float cw = fmaxf(fmaxf(px2, tx2) - fminf(px1, tx1), 0.f);
        const float ch = fmaxf(fmaxf(py2, ty2) - fminf(py1, ty1), 0.f);
        const float ac = cw * ch;
        const float giou = iou - (ac - uni) / ac;
        crow[(size_t)t * QQ] = (1.0f * cc + 5.0f * cb) + 2.0f * (-giou);
    }
}

// ---------------------------------------------------------------------------
// Kernel 2: Jonker-Volgenant shortest-augmenting-path LSA, one wave per batch.
// Rows = targets (80), cols = queries (600). Duals/minv in DOUBLE to match
// the reference's numpy float64 solver exactly (cost upcast f32->f64).
// Argmin tie-break = smallest column index (np.argmin first occurrence).
// ---------------------------------------------------------------------------
__global__ __launch_bounds__(64) void lsa_kernel(
    const float* __restrict__ cost,   // (B,NT,QQ)
    int* __restrict__ rows_out,       // (B,NT)
    int* __restrict__ cols_out)       // (B,NT)
{
    __shared__ double v[QQ];
    __shared__ double minv[QQ];
    __shared__ int    way[QQ];
    __shared__ int    used[QQ];
    __shared__ int    p[QQ];          // col -> assigned row, -1 free
    __shared__ double u[NT];
    __shared__ int    col4row[NT];

    const int b    = blockIdx.x;
    const int lane = threadIdx.x;
    const float* C = cost + (size_t)b * NT * QQ;

    for (int c = lane; c < QQ; c += 64) { v[c] = 0.0; p[c] = -1; }
    for (int t = lane; t < NT; t += 64) u[t] = 0.0;
    __syncthreads();

    for (int i = 0; i < NT; ++i) {
        for (int c = lane; c < QQ; c += 64) { minv[c] = INFINITY; used[c] = 0; }
        int j0 = -1;   // -1 == virtual start column (reference's j0=0)
        int j1 = -1;
        __syncthreads();
        for (;;) {
            if (j0 >= 0 && lane == 0) used[j0] = 1;
            __syncthreads();
            const int i0 = (j0 < 0) ? i : p[j0];
            const double ui0 = u[i0];
            const float* Crow = C + (size_t)i0 * QQ;

            double bestv = INFINITY;
            int    bestc = QQ;
            for (int k = 0; k < SLOTS; ++k) {
                const int c = lane + 64 * k;     // coalesced cost-row loads
                if (c < QQ && !used[c]) {
                    const double cur = (double)Crow[c] - ui0 - v[c];
                    double mv = minv[c];
                    if (cur < mv) { mv = cur; minv[c] = cur; way[c] = j0; }
                    if (mv < bestv) { bestv = mv; bestc = c; }  // c ascending => first-min
                }
            }
            // wave argmin, tie-break smallest column index
            for (int off = 32; off > 0; off >>= 1) {
                const double ov = __shfl_xor(bestv, off);
                const int    oc = __shfl_xor(bestc, off);
                if (ov < bestv || (ov == bestv && oc < bestc)) { bestv = ov; bestc = oc; }
            }
            const double delta = bestv;
            j1 = bestc;

            // dual update (each lane owns cols c ≡ lane mod 64 -> no races;
            // u[p[c]] targets are distinct rows across used columns)
            for (int k = 0; k < SLOTS; ++k) {
                const int c = lane + 64 * k;
                if (c < QQ) {
                    if (used[c]) { v[c] -= delta; u[p[c]] += delta; }
                    else          minv[c] -= delta;
                }
            }
            if (lane == 0) u[i] += delta;   // virtual column's row
            j0 = j1;
            __syncthreads();
            if (p[j1] < 0) break;           // reached a free column
        }
        // augment along the way[] chain (uniform scalar work)
        if (lane == 0) {
            int jj = j1;
            while (jj >= 0) {
                const int pr = way[jj];
                p[jj] = (pr < 0) ? i : p[pr];
                jj = pr;
            }
        }
        __syncthreads();
    }

    // emit pairs in increasing query order == reference's stable argsort
    for (int k = 0; k < SLOTS; ++k) {
        const int c = lane + 64 * k;
        if (c < QQ) { const int t = p[c]; if (t >= 0) col4row[t] = c; }
    }
    __syncthreads();
    for (int t = lane; t < NT; t += 64) {
        const int c = col4row[t];
        int rank = 0;
        for (int t2 = 0; t2 < NT; ++t2) rank += (col4row[t2] < c) ? 1 : 0;
        rows_out[b * NT + rank] = c;   // query index
        cols_out[b * NT + rank] = t;   // target index
    }
}

extern "C" void kernel_launch(void* const* d_in, const int* in_sizes, int n_in,
                              void* d_out, int out_size, void* d_ws, size_t ws_size,
                              hipStream_t stream) {
    (void)in_sizes; (void)n_in; (void)out_size; (void)ws_size;
    const float* logits  = (const float*)d_in[0];
    const float* pboxes  = (const float*)d_in[1];
    const int*   tlabels = (const int*)d_in[2];
    const float* tboxes  = (const float*)d_in[3];
    float* cost = (float*)d_ws;                 // (B,NT,QQ) f32 = 12.3 MB
    int*   out  = (int*)d_out;                  // rows (B,NT) then cols (B,NT), int32

    cost_kernel<<<dim3(BB * 3), 256, 0, stream>>>(logits, pboxes, tlabels, tboxes, cost);
    lsa_kernel<<<dim3(BB), 64, 0, stream>>>(cost, out, out + BB * NT);
}

// Round 2
// 318.523 us; speedup vs baseline: 1.8499x; 1.8499x over previous
//
#include <hip/hip_runtime.h>
#include <math.h>

#define BB 64
#define QQ 600
#define NT 80
#define NC 92
#define SLOTS 10   // ceil(600/64)
#define NROWS 24   // rows staged in static LDS (24*600*4 = 57.6 KB)

// ---------------------------------------------------------------------------
// Fused cost kernel: per (batch, 64-query tile): stage logits tile in LDS,
// sequential softmax stats (bitwise-identical to round-1 passing kernel),
// then cost[b][t][q] with the class gather as a conflict-free LDS read
// (stride 93, label uniform per wave).
// ---------------------------------------------------------------------------
__global__ __launch_bounds__(256) void cost_fused_kernel(
    const float* __restrict__ logits,   // (B,Q,NC)
    const float* __restrict__ pboxes,   // (B,Q,4)
    const int*   __restrict__ tlabels,  // (B,NT)
    const float* __restrict__ tboxes,   // (B,NT,4)
    float* __restrict__ cost)           // (B,NT,QQ)
{
    __shared__ float tile[64 * 93];     // padded: stride 93 -> conflict-free
    __shared__ float s_m[64], s_s[64];
    __shared__ float s_tb[NT * 4];
    __shared__ int   s_tl[NT];
    const int b  = blockIdx.x / 10;
    const int q0 = (blockIdx.x % 10) * 64;
    const int nq = min(64, QQ - q0);
    const int tid = threadIdx.x;

    const float* src = logits + ((size_t)b * QQ + q0) * NC;
    for (int idx = tid; idx < nq * NC; idx += 256) {
        const int qq = idx / NC;
        tile[qq * 93 + (idx - qq * NC)] = src[idx];   // coalesced global read
    }
    for (int i = tid; i < NT * 4; i += 256) s_tb[i] = tboxes[b * NT * 4 + i];
    for (int i = tid; i < NT;     i += 256) s_tl[i] = tlabels[b * NT + i];
    __syncthreads();

    if (tid < nq) {   // sequential max/sum: same op order as the passing kernel
        float m = -INFINITY;
        for (int c = 0; c < NC; ++c) m = fmaxf(m, tile[tid * 93 + c]);
        float s = 0.f;
        for (int c = 0; c < NC; ++c) s += expf(tile[tid * 93 + c] - m);
        s_m[tid] = m; s_s[tid] = s;
    }
    __syncthreads();

    const int qq    = tid & 63;      // lane = query within tile
    const int tpart = tid >> 6;      // wave = 20-target chunk
    const int q     = q0 + qq;
    if (qq >= nq) return;            // no barriers after this point

    const float* pb = pboxes + ((size_t)b * QQ + q) * 4;
    const float px1 = pb[0], py1 = pb[1], px2 = pb[2], py2 = pb[3];
    const float pa  = (px2 - px1) * (py2 - py1);
    const float m = s_m[qq], s = s_s[qq];
    float* crow = cost + (size_t)b * NT * QQ + q;

    for (int tt = 0; tt < 20; ++tt) {
        const int t   = tpart * 20 + tt;
        const int lbl = s_tl[t];                       // uniform per wave
        const float cc = -(expf(tile[qq * 93 + lbl] - m) / s);
        const float tx1 = s_tb[t*4+0], ty1 = s_tb[t*4+1];
        const float tx2 = s_tb[t*4+2], ty2 = s_tb[t*4+3];
        const float cb = fabsf(px1-tx1) + fabsf(py1-ty1)
                       + fabsf(px2-tx2) + fabsf(py2-ty2);
        const float ta = (tx2 - tx1) * (ty2 - ty1);
        const float iw = fmaxf(fminf(px2, tx2) - fmaxf(px1, tx1), 0.f);
        const float ih = fmaxf(fminf(py2, ty2) - fmaxf(py1, ty1), 0.f);
        const float inter = iw * ih;
        const float uni   = pa + ta - inter;
        const float iou   = inter / uni;
        const float cw = fmaxf(fmaxf(px2, tx2) - fminf(px1, tx1), 0.f);
        const float ch = fmaxf(fmaxf(py2, ty2) - fminf(py1, ty1), 0.f);
        const float ac = cw * ch;
        const float giou = iou - (ac - uni) / ac;
        crow[(size_t)t * QQ] = (1.0f * cc + 5.0f * cb) + 2.0f * (-giou);
    }
}

// ---------------------------------------------------------------------------
// LSA: barrier-free register-resident inner loop, one wave per batch.
// Math op-order is bit-identical to the e-maxx/numpy-f64 reference.
// ---------------------------------------------------------------------------
__global__ __launch_bounds__(64) void lsa_kernel(
    const float* __restrict__ cost,   // (B,NT,QQ)
    int* __restrict__ rows_out,       // (B,NT)
    int* __restrict__ cols_out)       // (B,NT)
{
    __shared__ float  crows[NROWS * QQ];   // rows 0..23 cached (57.6 KB)
    __shared__ double u[NT];
    __shared__ int    pA[QQ];
    __shared__ int    wayA[QQ];
    __shared__ int    c4r[NT];

    const int b    = blockIdx.x;
    const int lane = threadIdx.x;
    const float* C = cost + (size_t)b * NT * QQ;

    // stage rows 0..NROWS-1 (float4, coalesced)
    {
        const float4* C4 = (const float4*)C;
        float4* L4 = (float4*)crows;
        for (int idx = lane; idx < NROWS * QQ / 4; idx += 64) L4[idx] = C4[idx];
    }
    for (int t = lane; t < NT; t += 64) u[t] = 0.0;
    for (int c = lane; c < QQ; c += 64) pA[c] = -1;

    // per-lane state: lane owns columns c = lane + 64k
    double v_[SLOTS], minv_[SLOTS];
    int p_[SLOTS];
    #pragma unroll
    for (int k = 0; k < SLOTS; ++k) { v_[k] = 0.0; p_[k] = -1; }
    __syncthreads();

    for (int i = 0; i < NT; ++i) {
        #pragma unroll
        for (int k = 0; k < SLOTS; ++k) minv_[k] = INFINITY;
        unsigned usedm = 0;
        int j0 = -1;
        int i0 = i;
        double ui0 = u[i];                 // broadcast LDS read
        float rowv[SLOTS];
        if (i0 < NROWS) {
            const float* rp = crows + i0 * QQ;
            #pragma unroll
            for (int k = 0; k < SLOTS; ++k) { const int c = lane + 64*k; rowv[k] = (c < QQ) ? rp[c] : 0.f; }
        } else {
            const float* rp = C + (size_t)i0 * QQ;
            #pragma unroll
            for (int k = 0; k < SLOTS; ++k) { const int c = lane + 64*k; rowv[k] = (c < QQ) ? rp[c] : 0.f; }
        }
        int j1, i1;

        for (;;) {
            // mark j0 used (register bitmask, owner lane)
            if (j0 >= 0 && (j0 & 63) == lane) usedm |= 1u << (j0 >> 6);

            // scan + fused argmin (first-occurrence tie-break: ascending c)
            double bestv = INFINITY; int bestc = QQ;
            #pragma unroll
            for (int k = 0; k < SLOTS; ++k) {
                const int c = lane + 64 * k;
                if (c < QQ && !((usedm >> k) & 1u)) {
                    const double cur = ((double)rowv[k] - ui0) - v_[k];
                    if (cur < minv_[k]) { minv_[k] = cur; wayA[c] = j0; }
                    if (minv_[k] < bestv) { bestv = minv_[k]; bestc = c; }
                }
            }
            // wave butterfly argmin, smallest-index tie-break
            #pragma unroll
            for (int off = 32; off > 0; off >>= 1) {
                const double ov = __shfl_xor(bestv, off);
                const int    oc = __shfl_xor(bestc, off);
                if (ov < bestv || (ov == bestv && oc < bestc)) { bestv = ov; bestc = oc; }
            }
            const double delta = bestv;
            j1 = bestc;

            // i1 = p[j1] via register select (slot uniform) + shuffle
            {
                const int slot = j1 >> 6, lj = j1 & 63;
                int myp = p_[0];
                #pragma unroll
                for (int k = 1; k < SLOTS; ++k) if (slot == k) myp = p_[k];
                i1 = __shfl(myp, lj);
            }

            // prefetch next row's u and cost row (row i1 is NOT in the tree,
            // so this iteration's dual update cannot touch u[i1])
            double ui_next = 0.0;
            float rown[SLOTS];
            if (i1 >= 0) {
                ui_next = u[i1];
                if (i1 < NROWS) {
                    const float* rp = crows + i1 * QQ;
                    #pragma unroll
                    for (int k = 0; k < SLOTS; ++k) { const int c = lane + 64*k; rown[k] = (c < QQ) ? rp[c] : 0.f; }
                } else {
                    const float* rp = C + (size_t)i1 * QQ;
                    #pragma unroll
                    for (int k = 0; k < SLOTS; ++k) { const int c = lane + 64*k; rown[k] = (c < QQ) ? rp[c] : 0.f; }
                }
            }

            // dual update: registers for v/minv; LDS RMW for u (distinct rows,
            // same owner lane every iteration -> same-thread ordering only)
            #pragma unroll
            for (int k = 0; k < SLOTS; ++k) {
                const int c = lane + 64 * k;
                if (c < QQ) {
                    if ((usedm >> k) & 1u) { v_[k] -= delta; u[p_[k]] += delta; }
                    else                     minv_[k] -= delta;
                }
            }
            if (lane == 0) u[i] += delta;   // virtual column's row

            j0 = j1;
            if (i1 < 0) break;              // free column reached
            i0 = i1; ui0 = ui_next;
            #pragma unroll
            for (int k = 0; k < SLOTS; ++k) rowv[k] = rown[k];
        }

        __syncthreads();                    // flush wayA / u before the walk
        if (lane == 0) {                    // augment along way chain
            int jj = j1;
            while (jj >= 0) {
                const int pr = wayA[jj];
                pA[jj] = (pr < 0) ? i : pA[pr];
                jj = pr;
            }
        }
        __syncthreads();
        #pragma unroll
        for (int k = 0; k < SLOTS; ++k) {   // refresh register copy of p
            const int c = lane + 64 * k;
            p_[k] = (c < QQ) ? pA[c] : -1;
        }
    }

    // emit in increasing query order == reference's stable argsort
    #pragma unroll
    for (int k = 0; k < SLOTS; ++k) {
        const int c = lane + 64 * k;
        if (c < QQ) { const int t = pA[c]; if (t >= 0) c4r[t] = c; }
    }
    __syncthreads();
    for (int t = lane; t < NT; t += 64) {
        const int c = c4r[t];
        int rank = 0;
        for (int t2 = 0; t2 < NT; ++t2) rank += (c4r[t2] < c) ? 1 : 0;
        rows_out[b * NT + rank] = c;
        cols_out[b * NT + rank] = t;
    }
}

extern "C" void kernel_launch(void* const* d_in, const int* in_sizes, int n_in,
                              void* d_out, int out_size, void* d_ws, size_t ws_size,
                              hipStream_t stream) {
    (void)in_sizes; (void)n_in; (void)out_size; (void)ws_size;
    const float* logits  = (const float*)d_in[0];
    const float* pboxes  = (const float*)d_in[1];
    const int*   tlabels = (const int*)d_in[2];
    const float* tboxes  = (const float*)d_in[3];
    float* cost = (float*)d_ws;               // (B,NT,QQ) f32 = 12.3 MB
    int*   out  = (int*)d_out;

    cost_fused_kernel<<<dim3(BB * 10), 256, 0, stream>>>(logits, pboxes, tlabels, tboxes, cost);
    lsa_kernel<<<dim3(BB), 64, 0, stream>>>(cost, out, out + BB * NT);
}

// Round 3
// 239.316 us; speedup vs baseline: 2.4622x; 1.3310x over previous
//
#include <hip/hip_runtime.h>
#include <math.h>

#define BB 64
#define QQ 600
#define NT 80
#define NC 92
#define SLOTS 10   // ceil(600/64)

// ---------------------------------------------------------------------------
// Fused cost kernel (unchanged from round 2, validated): cost[b][t][q]
// ---------------------------------------------------------------------------
__global__ __launch_bounds__(256) void cost_fused_kernel(
    const float* __restrict__ logits,   // (B,Q,NC)
    const float* __restrict__ pboxes,   // (B,Q,4)
    const int*   __restrict__ tlabels,  // (B,NT)
    const float* __restrict__ tboxes,   // (B,NT,4)
    float* __restrict__ cost)           // (B,NT,QQ)
{
    __shared__ float tile[64 * 93];
    __shared__ float s_m[64], s_s[64];
    __shared__ float s_tb[NT * 4];
    __shared__ int   s_tl[NT];
    const int b  = blockIdx.x / 10;
    const int q0 = (blockIdx.x % 10) * 64;
    const int nq = min(64, QQ - q0);
    const int tid = threadIdx.x;

    const float* src = logits + ((size_t)b * QQ + q0) * NC;
    for (int idx = tid; idx < nq * NC; idx += 256) {
        const int qq = idx / NC;
        tile[qq * 93 + (idx - qq * NC)] = src[idx];
    }
    for (int i = tid; i < NT * 4; i += 256) s_tb[i] = tboxes[b * NT * 4 + i];
    for (int i = tid; i < NT;     i += 256) s_tl[i] = tlabels[b * NT + i];
    __syncthreads();

    if (tid < nq) {
        float m = -INFINITY;
        for (int c = 0; c < NC; ++c) m = fmaxf(m, tile[tid * 93 + c]);
        float s = 0.f;
        for (int c = 0; c < NC; ++c) s += expf(tile[tid * 93 + c] - m);
        s_m[tid] = m; s_s[tid] = s;
    }
    __syncthreads();

    const int qq    = tid & 63;
    const int tpart = tid >> 6;
    const int q     = q0 + qq;
    if (qq >= nq) return;

    const float* pb = pboxes + ((size_t)b * QQ + q) * 4;
    const float px1 = pb[0], py1 = pb[1], px2 = pb[2], py2 = pb[3];
    const float pa  = (px2 - px1) * (py2 - py1);
    const float m = s_m[qq], s = s_s[qq];
    float* crow = cost + (size_t)b * NT * QQ + q;

    for (int tt = 0; tt < 20; ++tt) {
        const int t   = tpart * 20 + tt;
        const int lbl = s_tl[t];
        const float cc = -(expf(tile[qq * 93 + lbl] - m) / s);
        const float tx1 = s_tb[t*4+0], ty1 = s_tb[t*4+1];
        const float tx2 = s_tb[t*4+2], ty2 = s_tb[t*4+3];
        const float cb = fabsf(px1-tx1) + fabsf(py1-ty1)
                       + fabsf(px2-tx2) + fabsf(py2-ty2);
        const float ta = (tx2 - tx1) * (ty2 - ty1);
        const float iw = fmaxf(fminf(px2, tx2) - fmaxf(px1, tx1), 0.f);
        const float ih = fmaxf(fminf(py2, ty2) - fmaxf(py1, ty1), 0.f);
        const float inter = iw * ih;
        const float uni   = pa + ta - inter;
        const float iou   = inter / uni;
        const float cw = fmaxf(fmaxf(px2, tx2) - fminf(px1, tx1), 0.f);
        const float ch = fmaxf(fmaxf(py2, ty2) - fminf(py1, ty1), 0.f);
        const float ac = cw * ch;
        const float giou = iou - (ac - uni) / ac;
        crow[(size_t)t * QQ] = (1.0f * cc + 5.0f * cb) + 2.0f * (-giou);
    }
}

// ---------------------------------------------------------------------------
// LSA with LAPJV preprocessing: row reduction + greedy assign (exact f32
// compares), then f64 shortest-augmenting-path only for unassigned rows.
// Maintains complementary slackness throughout -> exact optimal assignment
// (== reference, optimum unique for continuous random costs).
// ---------------------------------------------------------------------------
__global__ __launch_bounds__(64) void lsa_kernel(
    const float* __restrict__ cost,   // (B,NT,QQ)
    int* __restrict__ rows_out,       // (B,NT)
    int* __restrict__ cols_out)       // (B,NT)
{
    __shared__ double u[NT];
    __shared__ int    pA[QQ];
    __shared__ int    wayA[QQ];
    __shared__ int    c4r[NT];
    __shared__ int    unlist[NT];

    const int b    = blockIdx.x;
    const int lane = threadIdx.x;
    const float* C = cost + (size_t)b * NT * QQ;

    // per-lane state: lane owns columns c = lane + 64k
    double v_[SLOTS], minv_[SLOTS];
    int p_[SLOTS];
    #pragma unroll
    for (int k = 0; k < SLOTS; ++k) { v_[k] = 0.0; p_[k] = -1; }

    // ---- phase 1: row reduction + greedy (pure f32 compares, exact) ----
    int nun = 0;                       // uniform across lanes
    float rowv[SLOTS];
    {
        const float* rp = C;           // row 0
        #pragma unroll
        for (int k = 0; k < SLOTS; ++k) { const int c = lane + 64*k; rowv[k] = (c < QQ) ? rp[c] : 0.f; }
    }
    for (int i = 0; i < NT; ++i) {
        float rown[SLOTS];
        if (i + 1 < NT) {              // prefetch next row (independent)
            const float* rp = C + (size_t)(i + 1) * QQ;
            #pragma unroll
            for (int k = 0; k < SLOTS; ++k) { const int c = lane + 64*k; rown[k] = (c < QQ) ? rp[c] : 0.f; }
        }
        // per-lane argmin (ascending c => first occurrence)
        float bv = INFINITY; int bc = QQ;
        #pragma unroll
        for (int k = 0; k < SLOTS; ++k) {
            const int c = lane + 64 * k;
            if (c < QQ && rowv[k] < bv) { bv = rowv[k]; bc = c; }
        }
        #pragma unroll
        for (int off = 32; off > 0; off >>= 1) {
            const float ov = __shfl_xor(bv, off);
            const int   oc = __shfl_xor(bc, off);
            if (ov < bv || (ov == bv && oc < bc)) { bv = ov; bc = oc; }
        }
        if (lane == 0) u[i] = (double)bv;   // u[i] = row min (tight dual)
        // greedy: assign if argmin column free (check via owner lane's regs)
        const int slot = bc >> 6, lj = bc & 63;
        int sel = p_[0];
        #pragma unroll
        for (int k = 1; k < SLOTS; ++k) if (slot == k) sel = p_[k];
        const int ok = __shfl(sel < 0 ? 1 : 0, lj);
        if (ok) {
            if (lane == lj) {
                #pragma unroll
                for (int k = 0; k < SLOTS; ++k) if (k == slot) p_[k] = i;
            }
        } else {
            if (lane == 0) unlist[nun] = i;
            ++nun;                     // uniform
        }
        #pragma unroll
        for (int k = 0; k < SLOTS; ++k) rowv[k] = rown[k];
    }
    // publish p to LDS; make u/unlist visible
    #pragma unroll
    for (int k = 0; k < SLOTS; ++k) { const int c = lane + 64 * k; if (c < QQ) pA[c] = p_[k]; }
    __syncthreads();

    // ---- phase 2: SAP for the few unassigned rows (f64, exact) ----
    for (int ii = 0; ii < nun; ++ii) {
        const int i = unlist[ii];
        #pragma unroll
        for (int k = 0; k < SLOTS; ++k) minv_[k] = INFINITY;
        unsigned usedm = 0;
        int j0 = -1;
        double ui0 = u[i];
        {
            const float* rp = C + (size_t)i * QQ;
            #pragma unroll
            for (int k = 0; k < SLOTS; ++k) { const int c = lane + 64*k; rowv[k] = (c < QQ) ? rp[c] : 0.f; }
        }
        int j1, i1;

        for (;;) {
            if (j0 >= 0 && (j0 & 63) == lane) usedm |= 1u << (j0 >> 6);

            double bestv = INFINITY; int bestc = QQ;
            #pragma unroll
            for (int k = 0; k < SLOTS; ++k) {
                const int c = lane + 64 * k;
                if (c < QQ && !((usedm >> k) & 1u)) {
                    const double cur = ((double)rowv[k] - ui0) - v_[k];
                    if (cur < minv_[k]) { minv_[k] = cur; wayA[c] = j0; }
                    if (minv_[k] < bestv) { bestv = minv_[k]; bestc = c; }
                }
            }
            #pragma unroll
            for (int off = 32; off > 0; off >>= 1) {
                const double ov = __shfl_xor(bestv, off);
                const int    oc = __shfl_xor(bestc, off);
                if (ov < bestv || (ov == bestv && oc < bestc)) { bestv = ov; bestc = oc; }
            }
            const double delta = bestv;
            j1 = bestc;

            // i1 = p[j1] via register select + shuffle
            {
                const int slot = j1 >> 6, lj = j1 & 63;
                int myp = p_[0];
                #pragma unroll
                for (int k = 1; k < SLOTS; ++k) if (slot == k) myp = p_[k];
                i1 = __shfl(myp, lj);
            }

            // prefetch next row's u and cost row (row i1 not in tree yet)
            double ui_next = 0.0;
            float rown[SLOTS];
            if (i1 >= 0) {
                ui_next = u[i1];
                const float* rp = C + (size_t)i1 * QQ;
                #pragma unroll
                for (int k = 0; k < SLOTS; ++k) { const int c = lane + 64*k; rown[k] = (c < QQ) ? rp[c] : 0.f; }
            }

            // dual update (registers; LDS RMW for u, distinct rows per lane)
            #pragma unroll
            for (int k = 0; k < SLOTS; ++k) {
                const int c = lane + 64 * k;
                if (c < QQ) {
                    if ((usedm >> k) & 1u) { v_[k] -= delta; u[p_[k]] += delta; }
                    else                     minv_[k] -= delta;
                }
            }
            if (lane == 0) u[i] += delta;

            j0 = j1;
            if (i1 < 0) break;
            ui0 = ui_next;
            #pragma unroll
            for (int k = 0; k < SLOTS; ++k) rowv[k] = rown[k];
        }

        __syncthreads();
        if (lane == 0) {               // augment along way chain
            int jj = j1;
            while (jj >= 0) {
                const int pr = wayA[jj];
                pA[jj] = (pr < 0) ? i : pA[pr];
                jj = pr;
            }
        }
        __syncthreads();
        #pragma unroll
        for (int k = 0; k < SLOTS; ++k) {
            const int c = lane + 64 * k;
            p_[k] = (c < QQ) ? pA[c] : -1;
        }
    }

    // ---- emit in increasing query order (== reference's stable argsort) ----
    #pragma unroll
    for (int k = 0; k < SLOTS; ++k) {
        const int c = lane + 64 * k;
        if (c < QQ) { const int t = p_[k]; if (t >= 0) c4r[t] = c; }
    }
    __syncthreads();
    for (int t = lane; t < NT; t += 64) {
        const int c = c4r[t];
        int rank = 0;
        for (int t2 = 0; t2 < NT; ++t2) rank += (c4r[t2] < c) ? 1 : 0;
        rows_out[b * NT + rank] = c;
        cols_out[b * NT + rank] = t;
    }
}

extern "C" void kernel_launch(void* const* d_in, const int* in_sizes, int n_in,
                              void* d_out, int out_size, void* d_ws, size_t ws_size,
                              hipStream_t stream) {
    (void)in_sizes; (void)n_in; (void)out_size; (void)ws_size;
    const float* logits  = (const float*)d_in[0];
    const float* pboxes  = (const float*)d_in[1];
    const int*   tlabels = (const int*)d_in[2];
    const float* tboxes  = (const float*)d_in[3];
    float* cost = (float*)d_ws;               // (B,NT,QQ) f32 = 12.3 MB
    int*   out  = (int*)d_out;

    cost_fused_kernel<<<dim3(BB * 10), 256, 0, stream>>>(logits, pboxes, tlabels, tboxes, cost);
    lsa_kernel<<<dim3(BB), 64, 0, stream>>>(cost, out, out + BB * NT);
}

// Round 4
// 227.409 us; speedup vs baseline: 2.5911x; 1.0524x over previous
//
#include <hip/hip_runtime.h>
#include <math.h>

#define BB 64
#define QQ 600
#define NT 80
#define NC 92
#define SLOTS 10    // ceil(600/64)
#define NTILE 10    // 64-query tiles per batch
#define UCAP 576    // auction queue capacity (guard-bounded)

// ---------------------------------------------------------------------------
// Fused cost kernel + per-(row,tile) min/argmin partials.
// cost[b][t][q]; pminv/pmini[(b*NT+t)*NTILE + tile].
// ---------------------------------------------------------------------------
__global__ __launch_bounds__(256) void cost_fused_kernel(
    const float* __restrict__ logits,   // (B,Q,NC)
    const float* __restrict__ pboxes,   // (B,Q,4)
    const int*   __restrict__ tlabels,  // (B,NT)
    const float* __restrict__ tboxes,   // (B,NT,4)
    float* __restrict__ cost,           // (B,NT,QQ)
    float* __restrict__ pminv,          // (B,NT,NTILE)
    int*   __restrict__ pmini)          // (B,NT,NTILE)
{
    __shared__ float tile[64 * 93];
    __shared__ float s_m[64], s_s[64];
    __shared__ float s_tb[NT * 4];
    __shared__ int   s_tl[NT];
    const int b   = blockIdx.x / NTILE;
    const int tix = blockIdx.x % NTILE;
    const int q0  = tix * 64;
    const int nq  = min(64, QQ - q0);   // 24 for the last tile
    const int tid = threadIdx.x;

    const float* src = logits + ((size_t)b * QQ + q0) * NC;
    for (int idx = tid; idx < nq * NC; idx += 256) {
        const int qq = idx / NC;
        tile[qq * 93 + (idx - qq * NC)] = src[idx];
    }
    for (int i = tid; i < NT * 4; i += 256) s_tb[i] = tboxes[b * NT * 4 + i];
    for (int i = tid; i < NT;     i += 256) s_tl[i] = tlabels[b * NT + i];
    __syncthreads();

    if (tid < nq) {   // 4-way unrolled softmax stats (NC = 92 = 4*23)
        const float* r = &tile[tid * 93];
        float m0 = r[0], m1 = r[1], m2 = r[2], m3 = r[3];
        for (int c = 4; c < NC; c += 4) {
            m0 = fmaxf(m0, r[c]);   m1 = fmaxf(m1, r[c+1]);
            m2 = fmaxf(m2, r[c+2]); m3 = fmaxf(m3, r[c+3]);
        }
        const float m = fmaxf(fmaxf(m0, m1), fmaxf(m2, m3));
        float s0 = 0.f, s1 = 0.f, s2 = 0.f, s3 = 0.f;
        for (int c = 0; c < NC; c += 4) {
            s0 += expf(r[c]   - m); s1 += expf(r[c+1] - m);
            s2 += expf(r[c+2] - m); s3 += expf(r[c+3] - m);
        }
        s_m[tid] = m; s_s[tid] = (s0 + s1) + (s2 + s3);
    }
    __syncthreads();

    const int  qq    = tid & 63;
    const int  wv    = tid >> 6;      // wave -> 20-target chunk
    const int  q     = q0 + qq;
    const bool valid = qq < nq;       // keep all lanes alive for butterflies

    float px1 = 0.f, py1 = 0.f, px2 = 0.f, py2 = 0.f, pa = 0.f, m = 0.f, s = 1.f;
    if (valid) {
        const float* pb = pboxes + ((size_t)b * QQ + q) * 4;
        px1 = pb[0]; py1 = pb[1]; px2 = pb[2]; py2 = pb[3];
        pa  = (px2 - px1) * (py2 - py1);
        m = s_m[qq]; s = s_s[qq];
    }
    float* crow = cost + (size_t)b * NT * QQ + q;

    for (int tt = 0; tt < 20; ++tt) {
        const int t = wv * 20 + tt;
        float costv = INFINITY;
        if (valid) {
            const int lbl = s_tl[t];
            const float cc = -(expf(tile[qq * 93 + lbl] - m) / s);
            const float tx1 = s_tb[t*4+0], ty1 = s_tb[t*4+1];
            const float tx2 = s_tb[t*4+2], ty2 = s_tb[t*4+3];
            const float cb = fabsf(px1-tx1) + fabsf(py1-ty1)
                           + fabsf(px2-tx2) + fabsf(py2-ty2);
            const float ta = (tx2 - tx1) * (ty2 - ty1);
            const float iw = fmaxf(fminf(px2, tx2) - fmaxf(px1, tx1), 0.f);
            const float ih = fmaxf(fminf(py2, ty2) - fmaxf(py1, ty1), 0.f);
            const float inter = iw * ih;
            const float uni   = pa + ta - inter;
            const float iou   = inter / uni;
            const float cw = fmaxf(fmaxf(px2, tx2) - fminf(px1, tx1), 0.f);
            const float ch = fmaxf(fmaxf(py2, ty2) - fminf(py1, ty1), 0.f);
            const float ac = cw * ch;
            const float giou = iou - (ac - uni) / ac;
            costv = (1.0f * cc + 5.0f * cb) + 2.0f * (-giou);
            crow[(size_t)t * QQ] = costv;
        }
        // wave min/argmin over the 64-query tile (first-occurrence tie-break)
        float bv = costv; int bq = valid ? q : QQ;
        #pragma unroll
        for (int off = 32; off > 0; off >>= 1) {
            const float ov = __shfl_xor(bv, off);
            const int   oq = __shfl_xor(bq, off);
            if (ov < bv || (ov == bv && oq < bq)) { bv = ov; bq = oq; }
        }
        if (qq == 0) {
            pminv[((size_t)b * NT + t) * NTILE + tix] = bv;
            pmini[((size_t)b * NT + t) * NTILE + tix] = bq;
        }
    }
}

// ---------------------------------------------------------------------------
// LSA: greedy (precomputed argmins) -> LAPJV auction (min/2nd-min, f64)
// -> Dijkstra SAP epilogue for stragglers. Dual-feasible throughout => exact.
// ---------------------------------------------------------------------------
__global__ __launch_bounds__(64) void lsa_kernel(
    const float* __restrict__ cost,   // (B,NT,QQ)
    const float* __restrict__ pminv,  // (B,NT,NTILE)
    const int*   __restrict__ pmini,  // (B,NT,NTILE)
    int* __restrict__ rows_out,       // (B,NT)
    int* __restrict__ cols_out)       // (B,NT)
{
    __shared__ double u[NT];
    __shared__ int    pA[QQ];
    __shared__ int    wayA[QQ];
    __shared__ int    c4r[NT];
    __shared__ int    unlist[UCAP];
    __shared__ int    djk[NT];
    __shared__ float  rminv[NT];
    __shared__ int    rargA[NT];

    const int b    = blockIdx.x;
    const int lane = threadIdx.x;
    const float* C = cost + (size_t)b * NT * QQ;

    double v_[SLOTS], minv_[SLOTS];
    int p_[SLOTS];
    #pragma unroll
    for (int k = 0; k < SLOTS; ++k) { v_[k] = 0.0; p_[k] = -1; }
    #pragma unroll
    for (int k = 0; k < SLOTS; ++k) { const int c = lane + 64*k; if (c < QQ) pA[c] = -1; }

    // ---- phase 0: combine per-tile partials -> full-row min/argmin ----
    for (int t = lane; t < NT; t += 64) {
        const float* pv = pminv + ((size_t)b * NT + t) * NTILE;
        const int*   pi = pmini + ((size_t)b * NT + t) * NTILE;
        float bv = INFINITY; int bq = QQ;
        for (int k = 0; k < NTILE; ++k) {
            const float v = pv[k];
            if (v < bv) { bv = v; bq = pi[k]; }   // ascending tile => first-occurrence
        }
        rminv[t] = bv; rargA[t] = bq;
    }
    __syncthreads();

    // ---- phase 1: greedy row reduction (load-free) ----
    int nun = 0;   // uniform
    for (int i = 0; i < NT; ++i) {
        const int j = rargA[i];            // broadcast LDS read (uniform)
        if (lane == 0) u[i] = (double)rminv[i];
        const int cur = pA[j];
        if (cur < 0) {
            if (lane == 0) pA[j] = i;
            const int slot = j >> 6, lj = j & 63;
            if (lane == lj) {
                #pragma unroll
                for (int k = 0; k < SLOTS; ++k) if (k == slot) p_[k] = i;
            }
        } else {
            if (lane == 0) unlist[nun] = i;
            ++nun;
        }
    }

    // ---- phase 2a: auction / augmenting row reduction ----
    int head = 0, tail = nun, nd = 0;      // all uniform
    float rowv[SLOTS];
    while (head < tail) {
        if (head > 6 * NT) {               // runaway safety: drain to Dijkstra
            while (head < tail) {
                const int r = unlist[head];
                if (lane == 0) djk[nd] = r;
                ++nd; ++head;
            }
            break;
        }
        const int i = unlist[head]; ++head;
        const float* rp = C + (size_t)i * QQ;
        #pragma unroll
        for (int k = 0; k < SLOTS; ++k) { const int c = lane + 64*k; rowv[k] = (c < QQ) ? rp[c] : INFINITY; }

        double m1 = INFINITY, m2 = INFINITY; int j1 = QQ;
        #pragma unroll
        for (int k = 0; k < SLOTS; ++k) {
            const int c = lane + 64 * k;
            if (c < QQ) {
                const double key = (double)rowv[k] - v_[k];
                if (key < m1)      { m2 = m1; m1 = key; j1 = c; }
                else if (key < m2) { m2 = key; }
            }
        }
        #pragma unroll
        for (int off = 32; off > 0; off >>= 1) {
            const double om1 = __shfl_xor(m1, off);
            const int    oj1 = __shfl_xor(j1, off);
            const double om2 = __shfl_xor(m2, off);
            if (om1 < m1 || (om1 == m1 && oj1 < j1)) {
                m2 = fmin(m1, om2); m1 = om1; j1 = oj1;
            } else {
                m2 = fmin(om1, m2);
            }
        }
        // m1, j1, m2 now uniform
        const int k0 = pA[j1];
        if (m1 < m2) {
            const double diff = m2 - m1;
            const int slot = j1 >> 6, lj = j1 & 63;
            if (lane == lj) {
                #pragma unroll
                for (int k = 0; k < SLOTS; ++k) if (k == slot) { v_[k] -= diff; p_[k] = i; }
            }
            if (lane == 0) { u[i] = m2; pA[j1] = i; }
            if (k0 >= 0) {
                if (tail < UCAP) { if (lane == 0) unlist[tail] = k0; ++tail; }
                else             { if (lane == 0) djk[nd] = k0; ++nd; }
            }
        } else if (k0 < 0) {               // exact tie but column free
            const int slot = j1 >> 6, lj = j1 & 63;
            if (lane == lj) {
                #pragma unroll
                for (int k = 0; k < SLOTS; ++k) if (k == slot) p_[k] = i;
            }
            if (lane == 0) { u[i] = m2; pA[j1] = i; }
        } else {                           // tie + occupied: defer to Dijkstra
            if (lane == 0) djk[nd] = i;
            ++nd;
        }
    }
    __syncthreads();

    // ---- phase 2b: Dijkstra SAP for remaining rows (f64, exact) ----
    for (int ii = 0; ii < nd; ++ii) {
        const int i = djk[ii];
        #pragma unroll
        for (int k = 0; k < SLOTS; ++k) minv_[k] = INFINITY;
        unsigned usedm = 0;
        int j0 = -1;
        double ui0 = u[i];
        {
            const float* rp = C + (size_t)i * QQ;
            #pragma unroll
            for (int k = 0; k < SLOTS; ++k) { const int c = lane + 64*k; rowv[k] = (c < QQ) ? rp[c] : 0.f; }
        }
        int j1, i1;

        for (;;) {
            if (j0 >= 0 && (j0 & 63) == lane) usedm |= 1u << (j0 >> 6);

            double bestv = INFINITY; int bestc = QQ;
            #pragma unroll
            for (int k = 0; k < SLOTS; ++k) {
                const int c = lane + 64 * k;
                if (c < QQ && !((usedm >> k) & 1u)) {
                    const double cur = ((double)rowv[k] - ui0) - v_[k];
                    if (cur < minv_[k]) { minv_[k] = cur; wayA[c] = j0; }
                    if (minv_[k] < bestv) { bestv = minv_[k]; bestc = c; }
                }
            }
            #pragma unroll
            for (int off = 32; off > 0; off >>= 1) {
                const double ov = __shfl_xor(bestv, off);
                const int    oc = __shfl_xor(bestc, off);
                if (ov < bestv || (ov == bestv && oc < bestc)) { bestv = ov; bestc = oc; }
            }
            const double delta = bestv;
            j1 = bestc;

            {
                const int slot = j1 >> 6, lj = j1 & 63;
                int myp = p_[0];
                #pragma unroll
                for (int k = 1; k < SLOTS; ++k) if (slot == k) myp = p_[k];
                i1 = __shfl(myp, lj);
            }

            double ui_next = 0.0;
            float rown[SLOTS];
            if (i1 >= 0) {
                ui_next = u[i1];
                const float* rp = C + (size_t)i1 * QQ;
                #pragma unroll
                for (int k = 0; k < SLOTS; ++k) { const int c = lane + 64*k; rown[k] = (c < QQ) ? rp[c] : 0.f; }
            }

            #pragma unroll
            for (int k = 0; k < SLOTS; ++k) {
                const int c = lane + 64 * k;
                if (c < QQ) {
                    if ((usedm >> k) & 1u) { v_[k] -= delta; u[p_[k]] += delta; }
                    else                     minv_[k] -= delta;
                }
            }
            if (lane == 0) u[i] += delta;

            j0 = j1;
            if (i1 < 0) break;
            ui0 = ui_next;
            #pragma unroll
            for (int k = 0; k < SLOTS; ++k) rowv[k] = rown[k];
        }

        __syncthreads();
        if (lane == 0) {
            int jj = j1;
            while (jj >= 0) {
                const int pr = wayA[jj];
                pA[jj] = (pr < 0) ? i : pA[pr];
                jj = pr;
            }
        }
        __syncthreads();
        #pragma unroll
        for (int k = 0; k < SLOTS; ++k) {
            const int c = lane + 64 * k;
            p_[k] = (c < QQ) ? pA[c] : -1;
        }
    }

    // ---- emit in increasing query order ----
    #pragma unroll
    for (int k = 0; k < SLOTS; ++k) {
        const int c = lane + 64 * k;
        if (c < QQ) { const int t = pA[c]; if (t >= 0) c4r[t] = c; }
    }
    __syncthreads();
    for (int t = lane; t < NT; t += 64) {
        const int c = c4r[t];
        int rank = 0;
        for (int t2 = 0; t2 < NT; ++t2) rank += (c4r[t2] < c) ? 1 : 0;
        rows_out[b * NT + rank] = c;
        cols_out[b * NT + rank] = t;
    }
}

extern "C" void kernel_launch(void* const* d_in, const int* in_sizes, int n_in,
                              void* d_out, int out_size, void* d_ws, size_t ws_size,
                              hipStream_t stream) {
    (void)in_sizes; (void)n_in; (void)out_size; (void)ws_size;
    const float* logits  = (const float*)d_in[0];
    const float* pboxes  = (const float*)d_in[1];
    const int*   tlabels = (const int*)d_in[2];
    const float* tboxes  = (const float*)d_in[3];
    float* cost  = (float*)d_ws;                    // 12,288,000 B
    float* pminv = cost + (size_t)BB * NT * QQ;     // +204,800 B
    int*   pmini = (int*)(pminv + (size_t)BB * NT * NTILE);  // +204,800 B
    int*   out   = (int*)d_out;

    cost_fused_kernel<<<dim3(BB * NTILE), 256, 0, stream>>>(
        logits, pboxes, tlabels, tboxes, cost, pminv, pmini);
    lsa_kernel<<<dim3(BB), 64, 0, stream>>>(cost, pminv, pmini, out, out + BB * NT);
}

// Round 6
// 164.551 us; speedup vs baseline: 3.5809x; 1.3820x over previous
//
#include <hip/hip_runtime.h>
#include <math.h>

#define BB 64
#define QQ 600
#define NT 80
#define NC 92
#define SLOTS 10    // ceil(600/64)
#define NTILE 10    // 64-query tiles per batch
#define RQCAP 480   // re-bid queue capacity
#define STEPCAP 320 // fresh re-bid cap before draining to Dijkstra

// ---------------------------------------------------------------------------
// Fused cost kernel + per-(row,tile) (min, 2nd-min, argmin) partials.
// cost[b][t][q]; pm1/pm2/pmj[(b*NT+t)*NTILE + tile].
// ---------------------------------------------------------------------------
__global__ __launch_bounds__(256) void cost_fused_kernel(
    const float* __restrict__ logits,   // (B,Q,NC)
    const float* __restrict__ pboxes,   // (B,Q,4)
    const int*   __restrict__ tlabels,  // (B,NT)
    const float* __restrict__ tboxes,   // (B,NT,4)
    float* __restrict__ cost,           // (B,NT,QQ)
    float* __restrict__ pm1,            // (B,NT,NTILE)
    float* __restrict__ pm2,            // (B,NT,NTILE)
    int*   __restrict__ pmj)            // (B,NT,NTILE)
{
    __shared__ float tile[64 * 93];
    __shared__ float s_m[64], s_s[64];
    __shared__ float s_tb[NT * 4];
    __shared__ int   s_tl[NT];
    const int b   = blockIdx.x / NTILE;
    const int tix = blockIdx.x % NTILE;
    const int q0  = tix * 64;
    const int nq  = min(64, QQ - q0);   // 24 for the last tile
    const int tid = threadIdx.x;

    const float* src = logits + ((size_t)b * QQ + q0) * NC;
    for (int idx = tid; idx < nq * NC; idx += 256) {
        const int qq = idx / NC;
        tile[qq * 93 + (idx - qq * NC)] = src[idx];
    }
    for (int i = tid; i < NT * 4; i += 256) s_tb[i] = tboxes[b * NT * 4 + i];
    for (int i = tid; i < NT;     i += 256) s_tl[i] = tlabels[b * NT + i];
    __syncthreads();

    if (tid < nq) {   // 4-way unrolled softmax stats (NC = 92 = 4*23)
        const float* r = &tile[tid * 93];
        float m0 = r[0], m1 = r[1], m2 = r[2], m3 = r[3];
        for (int c = 4; c < NC; c += 4) {
            m0 = fmaxf(m0, r[c]);   m1 = fmaxf(m1, r[c+1]);
            m2 = fmaxf(m2, r[c+2]); m3 = fmaxf(m3, r[c+3]);
        }
        const float m = fmaxf(fmaxf(m0, m1), fmaxf(m2, m3));
        float s0 = 0.f, s1 = 0.f, s2 = 0.f, s3 = 0.f;
        for (int c = 0; c < NC; c += 4) {
            s0 += expf(r[c]   - m); s1 += expf(r[c+1] - m);
            s2 += expf(r[c+2] - m); s3 += expf(r[c+3] - m);
        }
        s_m[tid] = m; s_s[tid] = (s0 + s1) + (s2 + s3);
    }
    __syncthreads();

    const int  qq    = tid & 63;
    const int  wv    = tid >> 6;      // wave -> 20-target chunk
    const int  q     = q0 + qq;
    const bool valid = qq < nq;

    float px1 = 0.f, py1 = 0.f, px2 = 0.f, py2 = 0.f, pa = 0.f, m = 0.f, s = 1.f;
    if (valid) {
        const float* pb = pboxes + ((size_t)b * QQ + q) * 4;
        px1 = pb[0]; py1 = pb[1]; px2 = pb[2]; py2 = pb[3];
        pa  = (px2 - px1) * (py2 - py1);
        m = s_m[qq]; s = s_s[qq];
    }
    float* crow = cost + (size_t)b * NT * QQ + q;

    for (int tt = 0; tt < 20; ++tt) {
        const int t = wv * 20 + tt;
        float costv = INFINITY;
        if (valid) {
            const int lbl = s_tl[t];
            const float cc = -(expf(tile[qq * 93 + lbl] - m) / s);
            const float tx1 = s_tb[t*4+0], ty1 = s_tb[t*4+1];
            const float tx2 = s_tb[t*4+2], ty2 = s_tb[t*4+3];
            const float cb = fabsf(px1-tx1) + fabsf(py1-ty1)
                           + fabsf(px2-tx2) + fabsf(py2-ty2);
            const float ta = (tx2 - tx1) * (ty2 - ty1);
            const float iw = fmaxf(fminf(px2, tx2) - fmaxf(px1, tx1), 0.f);
            const float ih = fmaxf(fminf(py2, ty2) - fmaxf(py1, ty1), 0.f);
            const float inter = iw * ih;
            const float uni   = pa + ta - inter;
            const float iou   = inter / uni;
            const float cw = fmaxf(fmaxf(px2, tx2) - fminf(px1, tx1), 0.f);
            const float ch = fmaxf(fmaxf(py2, ty2) - fminf(py1, ty1), 0.f);
            const float ac = cw * ch;
            const float giou = iou - (ac - uni) / ac;
            costv = (1.0f * cc + 5.0f * cb) + 2.0f * (-giou);
            crow[(size_t)t * QQ] = costv;
        }
        // wave (min, 2nd-min, argmin); first-occurrence tie-break
        float b1 = costv, b2 = INFINITY; int bj = valid ? q : QQ;
        #pragma unroll
        for (int off = 32; off > 0; off >>= 1) {
            const float o1 = __shfl_xor(b1, off);
            const float o2 = __shfl_xor(b2, off);
            const int   oj = __shfl_xor(bj, off);
            if (o1 < b1 || (o1 == b1 && oj < bj)) {
                b2 = fminf(b1, o2); b1 = o1; bj = oj;
            } else {
                b2 = fminf(o1, b2);
            }
        }
        if (qq == 0) {
            const size_t idx = ((size_t)b * NT + t) * NTILE + tix;
            pm1[idx] = b1; pm2[idx] = b2; pmj[idx] = bj;
        }
    }
}

// ---------------------------------------------------------------------------
// Fresh row bid: (m1, j1, m2) of key = c[i,:] - v  (f64 exact), wave-wide.
// ---------------------------------------------------------------------------
__device__ inline void row_bid(const float* __restrict__ rp, const double* v_,
                               int lane, double& m1, double& m2, int& j1)
{
    float rowv[SLOTS];
    #pragma unroll
    for (int k = 0; k < SLOTS; ++k) { const int c = lane + 64*k; rowv[k] = (c < QQ) ? rp[c] : 0.f; }
    m1 = INFINITY; m2 = INFINITY; j1 = QQ;
    #pragma unroll
    for (int k = 0; k < SLOTS; ++k) {
        const int c = lane + 64 * k;
        if (c < QQ) {
            const double key = (double)rowv[k] - v_[k];
            if (key < m1)      { m2 = m1; m1 = key; j1 = c; }
            else if (key < m2) { m2 = key; }
        }
    }
    #pragma unroll
    for (int off = 32; off > 0; off >>= 1) {
        const double om1 = __shfl_xor(m1, off);
        const int    oj1 = __shfl_xor(j1, off);
        const double om2 = __shfl_xor(m2, off);
        if (om1 < m1 || (om1 == m1 && oj1 < j1)) {
            m2 = fmin(m1, om2); m1 = om1; j1 = oj1;
        } else {
            m2 = fmin(om1, m2);
        }
    }
}

// ---------------------------------------------------------------------------
// LSA. Duals: u = row mins (from precomputed bids), v starts at 0 and ONLY
// DECREASES (auction -(m2-m1), Dijkstra -delta) => v <= 0 throughout, which
// is the rectangular-LSA dual validity condition (round-5's v=colmin broke
// this and was the correctness bug). Stale bids stay valid while their argmin
// column's v is untouched (all other keys only increase). Dijkstra epilogue
// from this state => exact optimum == reference.
// ---------------------------------------------------------------------------
__global__ __launch_bounds__(256) void lsa_kernel(
    const float* __restrict__ cost,    // (B,NT,QQ)
    const float* __restrict__ pm1,     // (B,NT,NTILE)
    const float* __restrict__ pm2,     // (B,NT,NTILE)
    const int*   __restrict__ pmj,     // (B,NT,NTILE)
    int* __restrict__ rows_out,        // (B,NT)
    int* __restrict__ cols_out)        // (B,NT)
{
    __shared__ double u[NT];
    __shared__ double bidm1[NT], bidm2[NT];
    __shared__ int    bidj[NT];
    __shared__ int    pA[QQ];
    __shared__ int    wayA[QQ];
    __shared__ int    changedA[QQ];
    __shared__ int    c4r[NT];
    __shared__ int    rqA[RQCAP];
    __shared__ int    djkA[NT];

    const int b    = blockIdx.x;
    const int tid  = threadIdx.x;
    const int lane = tid & 63;
    const int wid  = tid >> 6;
    const float* C = cost + (size_t)b * NT * QQ;

    for (int c = tid; c < QQ; c += 256) { pA[c] = -1; changedA[c] = 0; }

    // ---- phase 0 (parallel): combine tile partials -> full-row bids ----
    if (tid < NT) {
        const int t = tid;
        const float* p1 = pm1 + ((size_t)b * NT + t) * NTILE;
        const float* p2 = pm2 + ((size_t)b * NT + t) * NTILE;
        const int*   pj = pmj + ((size_t)b * NT + t) * NTILE;
        float m1 = INFINITY, m2 = INFINITY; int j1 = QQ;
        for (int k = 0; k < NTILE; ++k) {       // ascending => first-occurrence
            const float a1 = p1[k], a2 = p2[k];
            const int   aj = pj[k];
            if (a1 < m1) { m2 = fminf(m1, a2); m1 = a1; j1 = aj; }
            else         { m2 = fminf(m2, a1); }
        }
        bidm1[t] = (double)m1; bidm2[t] = (double)m2; bidj[t] = j1;
        u[t] = (double)m1;      // feasible: keys only increase afterwards
    }
    __syncthreads();
    if (wid != 0) return;       // wave 0 continues alone; no barriers below

    double v_[SLOTS], minv_[SLOTS];
    int p_[SLOTS];
    #pragma unroll
    for (int k = 0; k < SLOTS; ++k) { v_[k] = 0.0; p_[k] = -1; }

    // ---- sequential auction (uniform control flow in wave 0) ----
    int pre = 0, rh = 0, rt = 0, nd = 0, steps = 0;
    while (pre < NT || rh < rt) {
        int i, j1; double m1, m2;
        if (pre < NT) {
            i = pre++;
            j1 = bidj[i];
            if (changedA[j1]) {                  // stale: defer for fresh bid
                if (rt < RQCAP) rqA[rt++] = i; else djkA[nd++] = i;
                continue;
            }
            m1 = bidm1[i]; m2 = bidm2[i];        // stale m2 is conservative/safe
        } else {
            i = rqA[rh++];
            if (++steps > STEPCAP) { djkA[nd++] = i; continue; }   // drain
            row_bid(C + (size_t)i * QQ, v_, lane, m1, m2, j1);     // fresh
            if (lane == 0) u[i] = m1;            // feasible forever (v only dec.)
        }
        const int prev = pA[j1];                 // broadcast LDS read
        if (m1 < m2) {
            const double diff = m2 - m1;
            const int slot = j1 >> 6, lj = j1 & 63;
            if (lane == lj) {
                #pragma unroll
                for (int k = 0; k < SLOTS; ++k) if (k == slot) { v_[k] -= diff; p_[k] = i; }
            }
            if (lane == 0) { pA[j1] = i; u[i] = m2; changedA[j1] = 1; }
            if (prev >= 0) { if (rt < RQCAP) rqA[rt++] = prev; else djkA[nd++] = prev; }
        } else if (prev < 0) {                   // exact tie, column free
            const int slot = j1 >> 6, lj = j1 & 63;
            if (lane == lj) {
                #pragma unroll
                for (int k = 0; k < SLOTS; ++k) if (k == slot) p_[k] = i;
            }
            if (lane == 0) { pA[j1] = i; u[i] = m2; }   // diff == 0: v unchanged
        } else {                                 // tie + occupied: Dijkstra
            djkA[nd++] = i;
        }
    }

    // ---- Dijkstra SAP for remaining rows (f64, exact; verified r2-r4) ----
    float rowv[SLOTS];
    for (int ii = 0; ii < nd; ++ii) {
        const int i = djkA[ii];
        #pragma unroll
        for (int k = 0; k < SLOTS; ++k) minv_[k] = INFINITY;
        unsigned usedm = 0;
        int j0 = -1;
        double ui0 = u[i];
        {
            const float* rp = C + (size_t)i * QQ;
            #pragma unroll
            for (int k = 0; k < SLOTS; ++k) { const int c = lane + 64*k; rowv[k] = (c < QQ) ? rp[c] : 0.f; }
        }
        int j1, i1;

        for (;;) {
            if (j0 >= 0 && (j0 & 63) == lane) usedm |= 1u << (j0 >> 6);

            double bestv = INFINITY; int bestc = QQ;
            #pragma unroll
            for (int k = 0; k < SLOTS; ++k) {
                const int c = lane + 64 * k;
                if (c < QQ && !((usedm >> k) & 1u)) {
                    const double cur = ((double)rowv[k] - ui0) - v_[k];
                    if (cur < minv_[k]) { minv_[k] = cur; wayA[c] = j0; }
                    if (minv_[k] < bestv) { bestv = minv_[k]; bestc = c; }
                }
            }
            #pragma unroll
            for (int off = 32; off > 0; off >>= 1) {
                const double ov = __shfl_xor(bestv, off);
                const int    oc = __shfl_xor(bestc, off);
                if (ov < bestv || (ov == bestv && oc < bestc)) { bestv = ov; bestc = oc; }
            }
            const double delta = bestv;
            j1 = bestc;

            {   // i1 = p[j1] via register select + shuffle
                const int slot = j1 >> 6, lj = j1 & 63;
                int myp = p_[0];
                #pragma unroll
                for (int k = 1; k < SLOTS; ++k) if (slot == k) myp = p_[k];
                i1 = __shfl(myp, lj);
            }

            double ui_next = 0.0;
            float rown[SLOTS];
            if (i1 >= 0) {      // prefetch next row (not in tree -> u stable)
                ui_next = u[i1];
                const float* rp = C + (size_t)i1 * QQ;
                #pragma unroll
                for (int k = 0; k < SLOTS; ++k) { const int c = lane + 64*k; rown[k] = (c < QQ) ? rp[c] : 0.f; }
            }

            #pragma unroll
            for (int k = 0; k < SLOTS; ++k) {
                const int c = lane + 64 * k;
                if (c < QQ) {
                    if ((usedm >> k) & 1u) { v_[k] -= delta; u[p_[k]] += delta; }
                    else                     minv_[k] -= delta;
                }
            }
            if (lane == 0) u[i] += delta;

            j0 = j1;
            if (i1 < 0) break;
            ui0 = ui_next;
            #pragma unroll
            for (int k = 0; k < SLOTS; ++k) rowv[k] = rown[k];
        }

        if (lane == 0) {        // augment along way chain
            int jj = j1;
            while (jj >= 0) {
                const int pr = wayA[jj];
                pA[jj] = (pr < 0) ? i : pA[pr];
                jj = pr;
            }
        }
        #pragma unroll
        for (int k = 0; k < SLOTS; ++k) {
            const int c = lane + 64 * k;
            p_[k] = (c < QQ) ? pA[c] : -1;
        }
    }

    // ---- emit in increasing query order (== reference's stable argsort) ----
    #pragma unroll
    for (int k = 0; k < SLOTS; ++k) {
        const int c = lane + 64 * k;
        if (c < QQ) { const int t = pA[c]; if (t >= 0) c4r[t] = c; }
    }
    for (int t = lane; t < NT; t += 64) {
        const int c = c4r[t];
        int rank = 0;
        for (int t2 = 0; t2 < NT; ++t2) rank += (c4r[t2] < c) ? 1 : 0;
        rows_out[b * NT + rank] = c;
        cols_out[b * NT + rank] = t;
    }
}

extern "C" void kernel_launch(void* const* d_in, const int* in_sizes, int n_in,
                              void* d_out, int out_size, void* d_ws, size_t ws_size,
                              hipStream_t stream) {
    (void)in_sizes; (void)n_in; (void)out_size; (void)ws_size;
    const float* logits  = (const float*)d_in[0];
    const float* pboxes  = (const float*)d_in[1];
    const int*   tlabels = (const int*)d_in[2];
    const float* tboxes  = (const float*)d_in[3];
    float* cost = (float*)d_ws;                          // 12,288,000 B
    float* pm1  = cost + (size_t)BB * NT * QQ;           // +204,800 B
    float* pm2  = pm1  + (size_t)BB * NT * NTILE;        // +204,800 B
    int*   pmj  = (int*)(pm2 + (size_t)BB * NT * NTILE); // +204,800 B
    int*   out  = (int*)d_out;

    cost_fused_kernel<<<dim3(BB * NTILE), 256, 0, stream>>>(
        logits, pboxes, tlabels, tboxes, cost, pm1, pm2, pmj);
    lsa_kernel<<<dim3(BB), 256, 0, stream>>>(cost, pm1, pm2, pmj, out, out + BB * NT);
}